// Round 2
// baseline (286.576 us; speedup 1.0000x reference)
//
#include <hip/hip_runtime.h>
#include <hip/hip_bf16.h>

// Problem constants (B, d, C, O) from reference setup_inputs()
static constexpr int BB = 8;
static constexpr int DD = 32768;
static constexpr int CC = 128;
static constexpr int OO = 128;

typedef __attribute__((ext_vector_type(8))) short short8;
typedef __attribute__((ext_vector_type(4))) float f32x4;

// ---------------- Kernel 1: column-sum over d ----------------
// xsum[b*C + c] = sum_i x[b,i,c].  2048 blocks (8 batches x 256 chunks of 128 rows).
__global__ __launch_bounds__(256) void colsum_k(const float* __restrict__ x,
                                                float* __restrict__ xsum) {
    int blk = blockIdx.x;          // 0..2047
    int b = blk >> 8;              // 256 chunks per batch
    int chunk = blk & 255;
    long base = ((long)b * DD + (long)chunk * 128) * CC;
    int t = threadIdx.x;
    int c4 = t & 31;               // which float4 of the 128-wide row
    int rg = t >> 5;               // row group 0..7
    f32x4 acc = {0.f, 0.f, 0.f, 0.f};
    const float* xp = x + base;
    #pragma unroll
    for (int r = rg; r < 128; r += 8) {
        const float4 v = *reinterpret_cast<const float4*>(xp + (long)r * CC + c4 * 4);
        acc[0] += v.x; acc[1] += v.y; acc[2] += v.z; acc[3] += v.w;
    }
    __shared__ f32x4 red[256];
    red[t] = acc;
    __syncthreads();
    if (t < 32) {
        f32x4 s = red[t];
        #pragma unroll
        for (int g = 1; g < 8; ++g) {
            f32x4 v = red[t + g * 32];
            s[0] += v[0]; s[1] += v[1]; s[2] += v[2]; s[3] += v[3];
        }
        float* dst = xsum + b * CC + t * 4;
        atomicAdd(dst + 0, s[0]);
        atomicAdd(dst + 1, s[1]);
        atomicAdd(dst + 2, s[2]);
        atomicAdd(dst + 3, s[3]);
    }
}

// ---------------- Kernel 2: alpha -> bf16, transposed [o][c] ----------------
__global__ __launch_bounds__(256) void alphacvt_k(const float* __restrict__ alpha,
                                                  ushort* __restrict__ alphaT) {
    int gid = blockIdx.x * 256 + threadIdx.x;  // 0..16383
    int o = gid >> 7, c = gid & 127;
    float v = alpha[c * OO + o];
    __hip_bfloat16 h = __float2bfloat16(v);
    alphaT[gid] = *reinterpret_cast<ushort*>(&h);
}

// ---------------- Kernel 3: add[b,o] = (xsum.beta + sum_c bias)/C ----------------
__global__ __launch_bounds__(256) void addvec_k(const float* __restrict__ xsum,
                                                const float* __restrict__ beta,
                                                const float* __restrict__ bias,
                                                float* __restrict__ add) {
    int gid = blockIdx.x * 256 + threadIdx.x;  // 0..1023
    int b = gid >> 7, o = gid & 127;
    float acc = 0.f;
    for (int c = 0; c < CC; ++c)
        acc += xsum[b * CC + c] * beta[c * OO + o] + bias[c * OO + o];
    add[gid] = acc * (1.0f / (float)CC);
}

// ---------------- Kernel 4: MFMA GEMM + epilogue ----------------
// 64-row tile per block, 4 waves x 16 rows, N=128 (8 n-frags), K=128 (4 k-steps).
// LDS rows padded to 136 shorts (272B) -> bank shift 4/row -> free 2-way conflict.
#define LSTR 136
__global__ __launch_bounds__(256) void gemm_k(const float* __restrict__ x,
                                              const ushort* __restrict__ alphaT,
                                              const float* __restrict__ add,
                                              float* __restrict__ out) {
    __shared__ ushort a_sh[128 * LSTR];  // alphaT [o][c] bf16, padded
    __shared__ ushort x_sh[64 * LSTR];   // x tile [row][c] bf16, padded

    int tile = blockIdx.x;               // 0..4095
    int t = threadIdx.x;
    long base = (long)tile * 64 * CC;    // flat float offset of this 64-row tile
    int b = (tile * 64) >> 15;           // 32768 rows per batch

    // stage alpha (bf16, [o][c]) -> LDS
    #pragma unroll
    for (int i = 0; i < 8; ++i) {
        int ci = i * 256 + t;            // 0..2047 chunks of 8 shorts
        int o = ci >> 4, cseg = (ci & 15) * 8;
        short8 v = *reinterpret_cast<const short8*>(alphaT + o * CC + cseg);
        *reinterpret_cast<short8*>(&a_sh[o * LSTR + cseg]) = v;
    }
    // stage x tile: fp32 global (coalesced 32B/lane) -> cvt bf16 -> LDS
    #pragma unroll
    for (int i = 0; i < 4; ++i) {
        int flat = (i * 256 + t) * 8;    // 0..8191
        int row = flat >> 7, c = flat & 127;
        const float* src = x + base + flat;
        float4 v0 = *reinterpret_cast<const float4*>(src);
        float4 v1 = *reinterpret_cast<const float4*>(src + 4);
        float f[8] = {v0.x, v0.y, v0.z, v0.w, v1.x, v1.y, v1.z, v1.w};
        short8 pack;
        #pragma unroll
        for (int j = 0; j < 8; ++j) {
            __hip_bfloat16 h = __float2bfloat16(f[j]);
            pack[j] = *reinterpret_cast<short*>(&h);
        }
        *reinterpret_cast<short8*>(&x_sh[row * LSTR + c]) = pack;
    }
    __syncthreads();

    int w = t >> 6;        // wave 0..3 -> rows w*16..w*16+15
    int l = t & 63;
    int lr = l & 15;       // A row within 16 / B col within 16 / C col
    int kq = l >> 4;       // k quadrant
    f32x4 acc[8];
    #pragma unroll
    for (int n = 0; n < 8; ++n) acc[n] = {0.f, 0.f, 0.f, 0.f};

    int arow = w * 16 + lr;
    #pragma unroll
    for (int kk = 0; kk < 4; ++kk) {
        short8 a = *reinterpret_cast<const short8*>(&x_sh[arow * LSTR + kk * 32 + kq * 8]);
        #pragma unroll
        for (int n = 0; n < 8; ++n) {
            short8 bf = *reinterpret_cast<const short8*>(&a_sh[(n * 16 + lr) * LSTR + kk * 32 + kq * 8]);
            acc[n] = __builtin_amdgcn_mfma_f32_16x16x32_bf16(a, bf, acc[n], 0, 0, 0);
        }
    }

    const float inv = 1.0f / (float)CC;
    #pragma unroll
    for (int n = 0; n < 8; ++n) {
        int o = n * 16 + lr;
        float addv = add[b * OO + o];
        #pragma unroll
        for (int j = 0; j < 4; ++j) {
            int row = w * 16 + kq * 4 + j;   // C/D layout: col=lane&15, row=(lane>>4)*4+j
            out[base + (long)row * OO + o] = acc[n][j] * inv + addv;
        }
    }
}

extern "C" void kernel_launch(void* const* d_in, const int* in_sizes, int n_in,
                              void* d_out, int out_size, void* d_ws, size_t ws_size,
                              hipStream_t stream) {
    const float* x     = (const float*)d_in[0];
    const float* alpha = (const float*)d_in[1];
    const float* beta  = (const float*)d_in[2];
    const float* bias  = (const float*)d_in[3];
    float* out = (float*)d_out;

    // ws layout: [0,4KB) xsum fp32 ; [4KB,8KB) add fp32 ; [8KB,40KB) alphaT bf16
    float*  xsum   = (float*)d_ws;
    float*  add    = (float*)((char*)d_ws + 4096);
    ushort* alphaT = (ushort*)((char*)d_ws + 8192);

    hipMemsetAsync(xsum, 0, BB * CC * sizeof(float), stream);
    colsum_k<<<2048, 256, 0, stream>>>(x, xsum);
    alphacvt_k<<<64, 256, 0, stream>>>(alpha, alphaT);
    addvec_k<<<4, 256, 0, stream>>>(xsum, beta, bias, add);
    gemm_k<<<4096, 256, 0, stream>>>(x, alphaT, add, out);
}

// Round 3
// 264.347 us; speedup vs baseline: 1.0841x; 1.0841x over previous
//
#include <hip/hip_runtime.h>
#include <hip/hip_bf16.h>

static constexpr int BB = 8;
static constexpr int DD = 32768;
static constexpr int CC = 128;
static constexpr int OO = 128;

typedef __attribute__((ext_vector_type(8))) short short8;
typedef __attribute__((ext_vector_type(4))) float f32x4;

// ---------------- Kernel 1: partial column sums (atomic-free) + alpha cvt tail ----
// blocks 0..1023: part[blk][c] = sum of 256 rows of x   (blk = b*128 + chunk)
// blocks 1024..1039: alphaT[o*128+c] = bf16(alpha[c*128+o])
__global__ __launch_bounds__(256) void colsum_k(const float* __restrict__ x,
                                                const float* __restrict__ alpha,
                                                float* __restrict__ part,
                                                ushort* __restrict__ alphaT) {
    int blk = blockIdx.x;
    int t = threadIdx.x;
    if (blk >= 1024) {           // alpha -> bf16 transposed, 16 blocks x 1024 elems
        int e = (blk - 1024) * 1024 + t * 4;
        #pragma unroll
        for (int j = 0; j < 4; ++j) {
            int g = e + j;
            int o = g >> 7, c = g & 127;
            __hip_bfloat16 h = __float2bfloat16(alpha[c * OO + o]);
            alphaT[g] = *reinterpret_cast<ushort*>(&h);
        }
        return;
    }
    int b = blk >> 7, chunk = blk & 127;
    long base = ((long)b * DD + (long)chunk * 256) * CC;
    int c4 = t & 31, rg = t >> 5;
    f32x4 acc = {0.f, 0.f, 0.f, 0.f};
    const float* xp = x + base + c4 * 4;
    for (int r = rg; r < 256; r += 8) {
        float4 v = *reinterpret_cast<const float4*>(xp + (long)r * CC);
        acc[0] += v.x; acc[1] += v.y; acc[2] += v.z; acc[3] += v.w;
    }
    __shared__ f32x4 red[256];
    red[t] = acc;
    __syncthreads();
    if (t < 32) {
        f32x4 s = red[t];
        #pragma unroll
        for (int g = 1; g < 8; ++g) {
            f32x4 v = red[t + g * 32];
            s[0] += v[0]; s[1] += v[1]; s[2] += v[2]; s[3] += v[3];
        }
        *reinterpret_cast<f32x4*>(part + blk * CC + t * 4) = s;
    }
}

// ---------------- Kernel 2: reduce partials -> xsum, then add[b,o] ----------------
// 8 blocks (one per batch). add[b,o] = (xsum[b,:].beta[:,o] + sum_c bias[c,o]) / C
__global__ __launch_bounds__(256) void addvec_k(const float* __restrict__ part,
                                                const float* __restrict__ beta,
                                                const float* __restrict__ bias,
                                                float* __restrict__ add) {
    int b = blockIdx.x;
    int t = threadIdx.x;
    int c = t & 127, half = t >> 7;
    __shared__ float xs2[2][128];
    __shared__ float xsum[128];
    float s = 0.f;
    for (int ch = half * 64; ch < half * 64 + 64; ++ch)
        s += part[(b * 128 + ch) * CC + c];
    xs2[half][c] = s;
    __syncthreads();
    if (t < 128) xsum[t] = xs2[0][t] + xs2[1][t];
    __syncthreads();
    float a = 0.f;
    for (int cc = half * 64; cc < half * 64 + 64; ++cc)
        a += xsum[cc] * beta[cc * OO + c] + bias[cc * OO + c];
    xs2[half][c] = a;
    __syncthreads();
    if (t < 128) add[b * OO + t] = (xs2[0][t] + xs2[1][t]) * (1.0f / (float)CC);
}

// ---------------- Kernel 3: persistent MFMA GEMM, x direct-to-reg ----------------
// 1024 blocks x 4 waves; each wave owns a 16-row tile, 4 tiles via grid-stride.
// alpha (bf16 [o][c]) staged to LDS ONCE; x loaded global->reg (no reuse -> no LDS).
// Operands swapped: mfma(alphaFrag, xFrag) -> D[row=o, col=xrow] so reg j walks
// 4 consecutive o -> coalesced float4 epilogue stores. Zero barriers in main loop.
#define LSTR 136
__global__ __launch_bounds__(256) void gemm_k(const float* __restrict__ x,
                                              const ushort* __restrict__ alphaT,
                                              const float* __restrict__ add,
                                              float* __restrict__ out) {
    __shared__ ushort a_sh[128 * LSTR];   // 34 KiB, padded: bank shift 4/row
    __shared__ float add_sh[BB * OO];     // 4 KiB
    int t = threadIdx.x;
    #pragma unroll
    for (int i = 0; i < 8; ++i) {
        int ci = i * 256 + t;
        int o = ci >> 4, cseg = (ci & 15) * 8;
        short8 v = *reinterpret_cast<const short8*>(alphaT + o * CC + cseg);
        *reinterpret_cast<short8*>(&a_sh[o * LSTR + cseg]) = v;
    }
    *reinterpret_cast<float4*>(&add_sh[t * 4]) = *reinterpret_cast<const float4*>(add + t * 4);
    __syncthreads();

    int w = t >> 6, l = t & 63;
    int lr = l & 15, kq = l >> 4;
    int wid = blockIdx.x * 4 + w;          // 0..4095
    const float inv = 1.0f / (float)CC;

    for (int it = 0; it < 4; ++it) {
        int tile = wid + it * 4096;        // 0..16383 (16 rows each)
        long base = (long)tile * 16 * CC;
        int b = tile >> 11;                // 2048 tiles per batch
        // x rows, fp32 global -> regs: lane covers 32 contiguous bytes per kk
        f32x4 xv[8];
        const float* xp = x + base + lr * CC + kq * 8;
        #pragma unroll
        for (int kk = 0; kk < 4; ++kk) {
            xv[kk * 2]     = *reinterpret_cast<const f32x4*>(xp + kk * 32);
            xv[kk * 2 + 1] = *reinterpret_cast<const f32x4*>(xp + kk * 32 + 4);
        }
        f32x4 acc[8];
        #pragma unroll
        for (int n = 0; n < 8; ++n) acc[n] = {0.f, 0.f, 0.f, 0.f};
        #pragma unroll
        for (int kk = 0; kk < 4; ++kk) {
            short8 af;
            #pragma unroll
            for (int j = 0; j < 4; ++j) {
                __hip_bfloat16 h0 = __float2bfloat16(xv[kk * 2][j]);
                af[j] = *reinterpret_cast<short*>(&h0);
                __hip_bfloat16 h1 = __float2bfloat16(xv[kk * 2 + 1][j]);
                af[4 + j] = *reinterpret_cast<short*>(&h1);
            }
            #pragma unroll
            for (int n = 0; n < 8; ++n) {
                short8 bf = *reinterpret_cast<const short8*>(
                    &a_sh[(n * 16 + lr) * LSTR + kk * 32 + kq * 8]);
                acc[n] = __builtin_amdgcn_mfma_f32_16x16x32_bf16(bf, af, acc[n], 0, 0, 0);
            }
        }
        // epilogue: lane lr stores o = n*16 + kq*4 + j  -> float4, 16 rows x 64B dense
        #pragma unroll
        for (int n = 0; n < 8; ++n) {
            int o0 = n * 16 + kq * 4;
            float4 ad = *reinterpret_cast<const float4*>(&add_sh[b * OO + o0]);
            float4 v;
            v.x = acc[n][0] * inv + ad.x;
            v.y = acc[n][1] * inv + ad.y;
            v.z = acc[n][2] * inv + ad.z;
            v.w = acc[n][3] * inv + ad.w;
            *reinterpret_cast<float4*>(out + base + (long)lr * OO + o0) = v;
        }
    }
}

extern "C" void kernel_launch(void* const* d_in, const int* in_sizes, int n_in,
                              void* d_out, int out_size, void* d_ws, size_t ws_size,
                              hipStream_t stream) {
    const float* x     = (const float*)d_in[0];
    const float* alpha = (const float*)d_in[1];
    const float* beta  = (const float*)d_in[2];
    const float* bias  = (const float*)d_in[3];
    float* out = (float*)d_out;

    // ws layout: [0,512K) part fp32[1024][128]; [512K,544K) alphaT bf16; [544K+12K..) add
    float*  part   = (float*)d_ws;
    ushort* alphaT = (ushort*)((char*)d_ws + 524288);
    float*  add    = (float*)((char*)d_ws + 557056);

    colsum_k<<<1040, 256, 0, stream>>>(x, alpha, part, alphaT);
    addvec_k<<<8,    256, 0, stream>>>(part, beta, bias, add);
    gemm_k<<<1024,   256, 0, stream>>>(x, alphaT, add, out);
}